// Round 7
// baseline (865.094 us; speedup 1.0000x reference)
//
#include <hip/hip_runtime.h>
#include <hip/hip_bf16.h>

#define DD 128
#define NPART 8

typedef __bf16 bf16x8 __attribute__((ext_vector_type(8)));
typedef float f32x4 __attribute__((ext_vector_type(4)));

__device__ inline unsigned short f2bf_rne(float f) {
    unsigned u = __float_as_uint(f);
    u += 0x7fff + ((u >> 16) & 1);
    return (unsigned short)(u >> 16);
}

// ---------------- CSR build ----------------
// nt loads: streaming src/dst must NOT allocate in L2, so the partition-local
// cnt/cursor/csr lines stay resident and merge fully before eviction.

__global__ __launch_bounds__(256) void hist_kernel(const int* __restrict__ dst,
                                                   int* __restrict__ cnt, int E, int psize) {
    int part = blockIdx.x & (NPART - 1);
    int lo = part * psize, hi = lo + psize;
    int stride = (gridDim.x >> 3) * 256;
    for (int e = (blockIdx.x >> 3) * 256 + threadIdx.x; e < E; e += stride) {
        int d = __builtin_nontemporal_load(&dst[e]);
        if (d >= lo && d < hi) atomicAdd(&cnt[d], 1);
    }
}

__global__ void scanA_kernel(const int* __restrict__ cnt, int* __restrict__ row_off,
                             int* __restrict__ partials, int N) {
    __shared__ int ls[256];
    int tid = threadIdx.x;
    int i = blockIdx.x * 1024 + tid * 4;
    int c0 = (i + 0 < N) ? cnt[i + 0] : 0;
    int c1 = (i + 1 < N) ? cnt[i + 1] : 0;
    int c2 = (i + 2 < N) ? cnt[i + 2] : 0;
    int c3 = (i + 3 < N) ? cnt[i + 3] : 0;
    int tot = c0 + c1 + c2 + c3;
    ls[tid] = tot;
    __syncthreads();
    for (int off = 1; off < 256; off <<= 1) {
        int v = (tid >= off) ? ls[tid - off] : 0;
        __syncthreads();
        ls[tid] += v;
        __syncthreads();
    }
    int excl = ls[tid] - tot;
    if (tid == 255) partials[blockIdx.x] = ls[255];
    int e0 = excl, e1 = e0 + c0, e2 = e1 + c1, e3 = e2 + c2;
    if (i + 0 < N) row_off[i + 0] = e0;
    if (i + 1 < N) row_off[i + 1] = e1;
    if (i + 2 < N) row_off[i + 2] = e2;
    if (i + 3 < N) row_off[i + 3] = e3;
}

__global__ __launch_bounds__(256) void scanB_kernel(int* partials, int nb) {
    __shared__ int ls[256];
    int tid = threadIdx.x;
    int base = 0;
    for (int c = 0; c < nb; c += 256) {
        int v = (c + tid < nb) ? partials[c + tid] : 0;
        ls[tid] = v;
        __syncthreads();
        for (int off = 1; off < 256; off <<= 1) {
            int t = (tid >= off) ? ls[tid - off] : 0;
            __syncthreads();
            ls[tid] += t;
            __syncthreads();
        }
        if (c + tid < nb) partials[c + tid] = ls[tid] - v + base;
        int tot = ls[255];
        __syncthreads();
        base += tot;
    }
}

__global__ void scanC_kernel(const int* __restrict__ cnt, int* __restrict__ row_off,
                             int* __restrict__ cursor, float* __restrict__ inv_deg,
                             const int* __restrict__ partials, int N) {
    int tid = threadIdx.x;
    int i = blockIdx.x * 1024 + tid * 4;
    int add = partials[blockIdx.x];
#pragma unroll
    for (int m = 0; m < 4; m++) {
        int idx = i + m;
        if (idx < N) {
            int v = row_off[idx] + add;
            row_off[idx] = v;
            cursor[idx] = v;
            int c = cnt[idx];
            inv_deg[idx] = 1.0f / (float)(c + 1);
            if (idx == N - 1) row_off[N] = v + c;
        }
    }
}

__global__ __launch_bounds__(256) void scatter_kernel(const int* __restrict__ src,
                                                      const int* __restrict__ dst,
                                                      int* __restrict__ cursor,
                                                      int* __restrict__ csr, int E, int psize) {
    int part = blockIdx.x & (NPART - 1);
    int lo = part * psize, hi = lo + psize;
    int stride = (gridDim.x >> 3) * 256;
    for (int e = (blockIdx.x >> 3) * 256 + threadIdx.x; e < E; e += stride) {
        int d = __builtin_nontemporal_load(&dst[e]);
        if (d >= lo && d < hi) {
            int s = __builtin_nontemporal_load(&src[e]);
            int pos = atomicAdd(&cursor[d], 1);
            csr[pos] = s;
        }
    }
}

// ---------------- x -> bf16 ----------------

__global__ __launch_bounds__(256) void tobf16_kernel(const float* __restrict__ x,
                                                     unsigned short* __restrict__ h, long total4) {
    long idx = (long)blockIdx.x * 256 + threadIdx.x;
    if (idx >= total4) return;
    float4 v = ((const float4*)x)[idx];
    ushort4 o;
    o.x = f2bf_rne(v.x); o.y = f2bf_rne(v.y); o.z = f2bf_rne(v.z); o.w = f2bf_rne(v.w);
    ((ushort4*)h)[idx] = o;
}

// ---------------- gather: pure bf16 neighbor-sum + self, bf16 out ----------------
// one wave per node; 4 lane-groups of 16 handle 4 edges concurrently;
// each lane owns 8 columns (one uint4 = 16B). 16-edge unroll -> 4 loads in flight.
// csr stream read nt so it doesn't evict the reused feature array from L2.

#define ACC8(u)                                                         \
    do {                                                                \
        a[0] += __uint_as_float((u).x << 16);                           \
        a[1] += __uint_as_float((u).x & 0xffff0000u);                   \
        a[2] += __uint_as_float((u).y << 16);                           \
        a[3] += __uint_as_float((u).y & 0xffff0000u);                   \
        a[4] += __uint_as_float((u).z << 16);                           \
        a[5] += __uint_as_float((u).z & 0xffff0000u);                   \
        a[6] += __uint_as_float((u).w << 16);                           \
        a[7] += __uint_as_float((u).w & 0xffff0000u);                   \
    } while (0)

__global__ __launch_bounds__(256) void gather_kernel(const uint4* __restrict__ prev4,
                                                     const int* __restrict__ row_off,
                                                     const int* __restrict__ csr,
                                                     uint4* __restrict__ out4, int N) {
    int node = blockIdx.x * 4 + (threadIdx.x >> 6);
    if (node >= N) return;
    int lane = threadIdx.x & 63;
    int g = lane >> 4, c = lane & 15;
    float a[8];
#pragma unroll
    for (int j = 0; j < 8; j++) a[j] = 0.f;
    int e = row_off[node], end = row_off[node + 1];
    for (; e + 16 <= end; e += 16) {
        int ia = __builtin_nontemporal_load(&csr[e + g]);
        int ib = __builtin_nontemporal_load(&csr[e + 4 + g]);
        int ic = __builtin_nontemporal_load(&csr[e + 8 + g]);
        int id = __builtin_nontemporal_load(&csr[e + 12 + g]);
        uint4 ua = prev4[ia * 16 + c];
        uint4 ub = prev4[ib * 16 + c];
        uint4 uc = prev4[ic * 16 + c];
        uint4 ud = prev4[id * 16 + c];
        ACC8(ua);
        ACC8(ub);
        ACC8(uc);
        ACC8(ud);
    }
    if (e + 8 <= end) {
        int ia = __builtin_nontemporal_load(&csr[e + g]);
        int ib = __builtin_nontemporal_load(&csr[e + 4 + g]);
        uint4 ua = prev4[ia * 16 + c];
        uint4 ub = prev4[ib * 16 + c];
        ACC8(ua);
        ACC8(ub);
        e += 8;
    }
    if (e + 4 <= end) {
        int ia = __builtin_nontemporal_load(&csr[e + g]);
        uint4 ua = prev4[ia * 16 + c];
        ACC8(ua);
        e += 4;
    }
    {
        int rem = end - e;
        if (g < rem) {
            int ia = __builtin_nontemporal_load(&csr[e + g]);
            uint4 ua = prev4[ia * 16 + c];
            ACC8(ua);
        }
    }
#pragma unroll
    for (int j = 0; j < 8; j++) {
        a[j] += __shfl_xor(a[j], 16);
        a[j] += __shfl_xor(a[j], 32);
    }
    if (g == 0) {
        uint4 us = prev4[node * 16 + c];
        ACC8(us);  // self-loop message
        uint4 o;
        o.x = ((unsigned)f2bf_rne(a[1]) << 16) | f2bf_rne(a[0]);
        o.y = ((unsigned)f2bf_rne(a[3]) << 16) | f2bf_rne(a[2]);
        o.z = ((unsigned)f2bf_rne(a[5]) << 16) | f2bf_rne(a[4]);
        o.w = ((unsigned)f2bf_rne(a[7]) << 16) | f2bf_rne(a[6]);
        out4[node * 16 + c] = o;
    }
}

// ---------------- W split into bf16 hi/lo planes ----------------

__global__ void wsplit_kernel(const float* __restrict__ W0, const float* __restrict__ W1,
                              const float* __restrict__ W2, const float* __restrict__ W3,
                              const float* __restrict__ W4, unsigned short* __restrict__ whl) {
    int idx = blockIdx.x * 256 + threadIdx.x;  // < 5*16384
    int l = idx >> 14, r = idx & 16383;
    const float* W = (l == 0) ? W0 : (l == 1) ? W1 : (l == 2) ? W2 : (l == 3) ? W3 : W4;
    float x = W[r];
    unsigned u = __float_as_uint(x);
    unsigned short h = (unsigned short)(u >> 16);
    float hf = __uint_as_float(u & 0xffff0000u);
    float lo = x - hf;  // exact
    unsigned short lw = (unsigned short)(__float_as_uint(lo) >> 16);
    whl[l * 32768 + r] = h;
    whl[l * 32768 + 16384 + r] = lw;
}

// ---------------- MFMA GEMM ----------------
// raw_agg = (Sg @ W^T) * inv_deg[row] + b[col]; 2-term split-bf16 (W hi/lo).
// W plane staged in LDS (hi phase, then lo phase) -> inner loop is pure LDS+MFMA.
// Writes raw agg as packed bf16; accumulates raw BN stats via atomics.

__global__ __launch_bounds__(256) void mgemm_kernel(const unsigned short* __restrict__ Sg,
                                                    unsigned short* __restrict__ hb,
                                                    const unsigned short* __restrict__ Whl,
                                                    const float* __restrict__ bias,
                                                    const float* __restrict__ inv_deg,
                                                    float* __restrict__ stats, int N) {
    __shared__ unsigned short SL[128 * 128];  // S tile, XOR-swizzled 16B chunks
    __shared__ unsigned short WL[128 * 128];  // W plane (hi, then lo), same swizzle
    const int t = threadIdx.x;
    const int i0 = blockIdx.x * 128;

    // stage S tile + Wh plane
#pragma unroll
    for (int b = 0; b < 8; b++) {
        int f = b * 256 + t;
        int r = f >> 4, k8 = f & 15;
        int row = i0 + r;
        uint4 v = make_uint4(0u, 0u, 0u, 0u);
        if (row < N) v = *(const uint4*)&Sg[(size_t)row * 128 + k8 * 8];
        int lbase = r * 128 + ((k8 ^ (r & 7)) * 8);
        *(uint4*)(SL + lbase) = v;
        uint4 wv = *(const uint4*)&Whl[f * 8];
        *(uint4*)(WL + lbase) = wv;
    }
    __syncthreads();

    const int w = t >> 6, l = t & 63;
    const int ll = l & 15, lh = l >> 4;
    const int r0 = w * 32 + ll, r1 = r0 + 16;

    // A-fragments to registers (reused in both phases)
    bf16x8 a0[4], a1[4];
#pragma unroll
    for (int ks = 0; ks < 4; ks++) {
        int k8 = ks * 4 + lh;
        a0[ks] = *(const bf16x8*)(SL + r0 * 128 + ((k8 ^ (r0 & 7)) * 8));
        a1[ks] = *(const bf16x8*)(SL + r1 * 128 + ((k8 ^ (r1 & 7)) * 8));
    }

    f32x4 acc[2][8];
#pragma unroll
    for (int st = 0; st < 2; st++)
#pragma unroll
        for (int jt = 0; jt < 8; jt++) acc[st][jt] = (f32x4){0.f, 0.f, 0.f, 0.f};

    // hi phase
#pragma unroll
    for (int ks = 0; ks < 4; ks++) {
        int k8 = ks * 4 + lh;
#pragma unroll
        for (int jt = 0; jt < 8; jt++) {
            int wrow = jt * 16 + ll;
            bf16x8 bh = *(const bf16x8*)(WL + wrow * 128 + ((k8 ^ (wrow & 7)) * 8));
            acc[0][jt] = __builtin_amdgcn_mfma_f32_16x16x32_bf16(a0[ks], bh, acc[0][jt], 0, 0, 0);
            acc[1][jt] = __builtin_amdgcn_mfma_f32_16x16x32_bf16(a1[ks], bh, acc[1][jt], 0, 0, 0);
        }
    }
    __syncthreads();
    // stage Wl plane
#pragma unroll
    for (int b = 0; b < 8; b++) {
        int f = b * 256 + t;
        int r = f >> 4, k8 = f & 15;
        uint4 wv = *(const uint4*)&Whl[16384 + f * 8];
        *(uint4*)(WL + r * 128 + ((k8 ^ (r & 7)) * 8)) = wv;
    }
    __syncthreads();
    // lo phase
#pragma unroll
    for (int ks = 0; ks < 4; ks++) {
        int k8 = ks * 4 + lh;
#pragma unroll
        for (int jt = 0; jt < 8; jt++) {
            int wrow = jt * 16 + ll;
            bf16x8 bl = *(const bf16x8*)(WL + wrow * 128 + ((k8 ^ (wrow & 7)) * 8));
            acc[0][jt] = __builtin_amdgcn_mfma_f32_16x16x32_bf16(a0[ks], bl, acc[0][jt], 0, 0, 0);
            acc[1][jt] = __builtin_amdgcn_mfma_f32_16x16x32_bf16(a1[ks], bl, acc[1][jt], 0, 0, 0);
        }
    }

    // epilogue: scale + bias, store bf16, accumulate column stats
    float bj[8];
#pragma unroll
    for (int jt = 0; jt < 8; jt++) bj[jt] = bias[jt * 16 + ll];
    float cs[8], cq[8];
#pragma unroll
    for (int jt = 0; jt < 8; jt++) { cs[jt] = 0.f; cq[jt] = 0.f; }
#pragma unroll
    for (int st = 0; st < 2; st++) {
#pragma unroll
        for (int reg = 0; reg < 4; reg++) {
            int row = i0 + w * 32 + st * 16 + lh * 4 + reg;
            bool valid = row < N;
            float sc = valid ? inv_deg[row] : 0.f;
#pragma unroll
            for (int jt = 0; jt < 8; jt++) {
                float o = acc[st][jt][reg] * sc + bj[jt];
                if (valid) {
                    hb[(size_t)row * 128 + jt * 16 + ll] = f2bf_rne(o);
                    cs[jt] += o;
                    cq[jt] += o * o;
                }
            }
        }
    }
#pragma unroll
    for (int jt = 0; jt < 8; jt++) {
        cs[jt] += __shfl_xor(cs[jt], 16);
        cs[jt] += __shfl_xor(cs[jt], 32);
        cq[jt] += __shfl_xor(cq[jt], 16);
        cq[jt] += __shfl_xor(cq[jt], 32);
    }
    __syncthreads();  // all LDS reads done; reuse SL for stats reduction
    float* sred = (float*)SL;  // [4 waves][2 stats][128 cols]
    if (l < 16) {
#pragma unroll
        for (int jt = 0; jt < 8; jt++) {
            sred[w * 256 + jt * 16 + l] = cs[jt];
            sred[w * 256 + 128 + jt * 16 + l] = cq[jt];
        }
    }
    __syncthreads();
    {
        int col = t & 127, s = t >> 7;
        float v = sred[0 * 256 + s * 128 + col] + sred[1 * 256 + s * 128 + col]
                + sred[2 * 256 + s * 128 + col] + sred[3 * 256 + s * 128 + col];
        atomicAdd(&stats[s * 128 + col], v);
    }
}

// ---------------- per-node BN normalize + ReLU (bf16 -> bf16) ----------------

__global__ __launch_bounds__(256) void norm_kernel(const uint4* __restrict__ hb4,
                                                   const float* __restrict__ stats_raw,
                                                   float invN,
                                                   uint4* __restrict__ hn4, int totalQ) {
    __shared__ float mls[128], rls[128];
    int t = threadIdx.x;
    if (t < 128) {
        float mean = stats_raw[t] * invN;
        float var = stats_raw[128 + t] * invN - mean * mean;
        mls[t] = mean;
        rls[t] = rsqrtf(var + 1e-5f);
    }
    __syncthreads();
    int stride = gridDim.x * 256;
    for (int idx = blockIdx.x * 256 + t; idx < totalQ; idx += stride) {
        int c0 = (idx & 15) * 8;
        uint4 u = hb4[idx];
        float v[8];
        v[0] = __uint_as_float(u.x << 16); v[1] = __uint_as_float(u.x & 0xffff0000u);
        v[2] = __uint_as_float(u.y << 16); v[3] = __uint_as_float(u.y & 0xffff0000u);
        v[4] = __uint_as_float(u.z << 16); v[5] = __uint_as_float(u.z & 0xffff0000u);
        v[6] = __uint_as_float(u.w << 16); v[7] = __uint_as_float(u.w & 0xffff0000u);
#pragma unroll
        for (int j = 0; j < 8; j++) v[j] = fmaxf((v[j] - mls[c0 + j]) * rls[c0 + j], 0.f);
        uint4 o;
        o.x = ((unsigned)f2bf_rne(v[1]) << 16) | f2bf_rne(v[0]);
        o.y = ((unsigned)f2bf_rne(v[3]) << 16) | f2bf_rne(v[2]);
        o.z = ((unsigned)f2bf_rne(v[5]) << 16) | f2bf_rne(v[4]);
        o.w = ((unsigned)f2bf_rne(v[7]) << 16) | f2bf_rne(v[6]);
        hn4[idx] = o;
    }
}

// ---------------- final normalize + relu: bf16 raw agg -> fp32 d_out ----------------

__global__ __launch_bounds__(256) void outnorm_kernel(const uint4* __restrict__ hb4,
                                                      const float* __restrict__ stats_raw,
                                                      float invN,
                                                      float4* __restrict__ out4, int totalQ) {
    __shared__ float mls[128], rls[128];
    int t = threadIdx.x;
    if (t < 128) {
        float mean = stats_raw[t] * invN;
        float var = stats_raw[128 + t] * invN - mean * mean;
        mls[t] = mean;
        rls[t] = rsqrtf(var + 1e-5f);
    }
    __syncthreads();
    int stride = gridDim.x * 256;
    for (int idx = blockIdx.x * 256 + t; idx < totalQ; idx += stride) {
        int c0 = (idx & 15) * 8;
        uint4 u = hb4[idx];
        float v[8];
        v[0] = __uint_as_float(u.x << 16); v[1] = __uint_as_float(u.x & 0xffff0000u);
        v[2] = __uint_as_float(u.y << 16); v[3] = __uint_as_float(u.y & 0xffff0000u);
        v[4] = __uint_as_float(u.z << 16); v[5] = __uint_as_float(u.z & 0xffff0000u);
        v[6] = __uint_as_float(u.w << 16); v[7] = __uint_as_float(u.w & 0xffff0000u);
#pragma unroll
        for (int j = 0; j < 8; j++) v[j] = fmaxf((v[j] - mls[c0 + j]) * rls[c0 + j], 0.f);
        float4 o0, o1;
        o0.x = v[0]; o0.y = v[1]; o0.z = v[2]; o0.w = v[3];
        o1.x = v[4]; o1.y = v[5]; o1.z = v[6]; o1.w = v[7];
        out4[idx * 2 + 0] = o0;
        out4[idx * 2 + 1] = o1;
    }
}

// ---------------- launch ----------------

extern "C" void kernel_launch(void* const* d_in, const int* in_sizes, int n_in,
                              void* d_out, int out_size, void* d_ws, size_t ws_size,
                              hipStream_t stream) {
    const float* x = (const float*)d_in[0];
    const int* ei = (const int*)d_in[1];
    int N = in_sizes[0] / DD;
    int E = in_sizes[1] / 2;
    const float* Wp[5];
    const float* bp[5];
    for (int l = 0; l < 5; l++) {
        Wp[l] = (const float*)d_in[2 + 2 * l];
        bp[l] = (const float*)d_in[3 + 2 * l];
    }

    char* ws = (char*)d_ws;
    size_t off = 0;
    auto alloc = [&](size_t bytes) -> char* {
        char* p = ws + off;
        off = (off + bytes + 511) & ~(size_t)511;
        return p;
    };
    int* cnt = (int*)alloc((size_t)N * 4);
    int* row_off = (int*)alloc(((size_t)N + 1) * 4);
    int* cursor = (int*)alloc((size_t)N * 4);
    int* partials = (int*)alloc(4096 * 4);
    float* inv_deg = (float*)alloc((size_t)N * 4);
    float* stats = (float*)alloc(5 * 256 * 4);
    unsigned short* whl = (unsigned short*)alloc(5 * 32768 * 2);
    int* csr = (int*)alloc((size_t)E * 4);
    unsigned short* hn = (unsigned short*)alloc((size_t)N * DD * 2);  // normalized input (bf16)
    unsigned short* Sg = (unsigned short*)alloc((size_t)N * DD * 2);  // gather output (bf16)
    unsigned short* hb = (unsigned short*)alloc((size_t)N * DD * 2);  // raw agg (bf16)
    (void)ws_size;

    const int* srcv = ei;
    const int* dstv = ei + E;

    hipMemsetAsync(cnt, 0, (size_t)N * 4, stream);
    hipMemsetAsync(stats, 0, 5 * 256 * 4, stream);

    wsplit_kernel<<<5 * 16384 / 256, 256, 0, stream>>>(Wp[0], Wp[1], Wp[2], Wp[3], Wp[4], whl);

    long total4 = (long)N * (DD / 4);
    tobf16_kernel<<<(int)((total4 + 255) / 256), 256, 0, stream>>>(x, hn, total4);

    int psize = (N + NPART - 1) / NPART;
    hist_kernel<<<NPART * 256, 256, 0, stream>>>(dstv, cnt, E, psize);
    int nb = (N + 1023) / 1024;
    scanA_kernel<<<nb, 256, 0, stream>>>(cnt, row_off, partials, N);
    scanB_kernel<<<1, 256, 0, stream>>>(partials, nb);
    scanC_kernel<<<nb, 256, 0, stream>>>(cnt, row_off, cursor, inv_deg, partials, N);
    scatter_kernel<<<NPART * 256, 256, 0, stream>>>(srcv, dstv, cursor, csr, E, psize);

    float invN = 1.0f / (float)N;
    int gblocks = (N + 3) / 4;
    int mblocks = (N + 127) / 128;
    int totalQ = N * 16;  // uint4 count

    for (int l = 0; l < 5; l++) {
        gather_kernel<<<gblocks, 256, 0, stream>>>((const uint4*)hn, row_off, csr,
                                                   (uint4*)Sg, N);
        mgemm_kernel<<<mblocks, 256, 0, stream>>>(Sg, hb, whl + l * 32768, bp[l], inv_deg,
                                                  stats + l * 256, N);
        if (l < 4) {
            norm_kernel<<<2048, 256, 0, stream>>>((const uint4*)hb, stats + l * 256, invN,
                                                  (uint4*)hn, totalQ);
        }
    }

    outnorm_kernel<<<2048, 256, 0, stream>>>((const uint4*)hb, stats + 4 * 256, invN,
                                             (float4*)d_out, totalQ);
}